// Round 6
// baseline (195.721 us; speedup 1.0000x reference)
//
#include <hip/hip_runtime.h>

// Reference: H=16, TP=8, C=257, T=S=128.  Output float32 (T,S,C,TP).
// ct_val[t,s,c,p] = (sum_p' d(sta[t,p'],pos[t,s,p']) - d(sta[t,p],pos[t,s,p])
//                    + d(cnc[t,c,p],pos[t,s,p])) / 8
// d(c1,c2,norm) = sign(c1>=0)*sign(c2>=0) * (1 - e/16) * norm
//   with e = frexp-exp(float(abs(c1)^abs(c2)+1)) = 32 - clz(xor+1)
//   => d = sign * norm * (clz(xor+1) - 16) / 16    (exact; verified r1==r2)
//
// Round 6: r4 structure + NONTEMPORAL output stores. r5's mirror experiment
// measured marginal write BW ~5.0 TB/s (vs 6.6 TB/s harness fills); output is
// write-once-never-read, so nt stores (early L2 evict) should close the gap.

namespace {
constexpr int kTP   = 8;
constexpr int kC    = 257;
constexpr int kT    = 128;
constexpr int kS    = 128;
constexpr int kSB   = 8;              // s per block
constexpr int kTile = kS / kSB;       // 16 s-tiles per t

typedef __attribute__((ext_vector_type(4))) int   int4v;
typedef __attribute__((ext_vector_type(4))) float float4v;
} // namespace

__global__ __launch_bounds__(256) void critigraph_kernel(
    const int*   __restrict__ sta,   // (T,TP)
    const int*   __restrict__ pos,   // (T,S,TP)
    const int*   __restrict__ cnc,   // (T,C,TP)
    const float* __restrict__ eu,    // (T,S)
    float*       __restrict__ out)   // (T,S,C,TP) f32
{
    __shared__ int   s_apos[kSB][kTP];   // |pos|
    __shared__ float s_np8[kSB][kTP];    // sign(pos)*norm/128
    __shared__ float s_csp[kSB][kTP];    // d(sta,pos)
    __shared__ float s_base8[kSB][kTP];  // (sum - csp[p]) / 8

    const int t   = blockIdx.x >> 4;
    const int s0  = (blockIdx.x & (kTile - 1)) * kSB;
    const int tid = threadIdx.x;

    if (tid < kSB * kTP) {
        const int sl = tid >> 3;
        const int p  = tid & 7;
        const int s  = s0 + sl;
        const int st = sta[t * kTP + p];
        const int po = pos[(t * kS + s) * kTP + p];
        const float norm = eu[t * kS + s];
        const int x = (abs(st) ^ abs(po)) + 1;
        const float f = (float)(__clz(x) - 16);
        const float v = f * norm * (1.0f / 16.0f);
        s_csp[sl][p]  = ((st ^ po) < 0) ? -v : v;
        s_apos[sl][p] = abs(po);
        s_np8[sl][p]  = (po >= 0 ? norm : -norm) * (1.0f / 128.0f);
    }
    __syncthreads();
    if (tid < kSB * kTP) {
        const int sl = tid >> 3;
        const int p  = tid & 7;
        float sum = 0.0f;
#pragma unroll
        for (int q = 0; q < kTP; ++q) sum += s_csp[sl][q];
        s_base8[sl][p] = (sum - s_csp[sl][p]) * 0.125f;
    }
    __syncthreads();

    // ---- main: candidate c = tid (256 of 257) ----
    {
        const int c = tid;
        const int* cb = cnc + ((size_t)t * kC + c) * kTP;   // 32B aligned
        const int4v lo = *(const int4v*)cb;
        const int4v hi = *(const int4v*)(cb + 4);
        int      acn[kTP];
        unsigned sg[kTP];
#pragma unroll
        for (int p = 0; p < kTP; ++p) {
            const int cn = (p < 4) ? lo[p] : hi[p - 4];
            acn[p] = abs(cn);
            sg[p]  = ((unsigned)cn) & 0x80000000u;
        }

        float* ob = out + ((size_t)(t * kS + s0) * kC + c) * kTP;
#pragma unroll
        for (int sl = 0; sl < kSB; ++sl) {
            const int4v   ap0 = *(const int4v*)&s_apos[sl][0];
            const int4v   ap1 = *(const int4v*)&s_apos[sl][4];
            const float4v np0 = *(const float4v*)&s_np8[sl][0];
            const float4v np1 = *(const float4v*)&s_np8[sl][4];
            const float4v b0  = *(const float4v*)&s_base8[sl][0];
            const float4v b1  = *(const float4v*)&s_base8[sl][4];

            float4v r0, r1;
#pragma unroll
            for (int p = 0; p < 4; ++p) {
                const int x = (acn[p] ^ ap0[p]) + 1;
                const float f = (float)(__clz(x) - 16);
                const float coeff = __int_as_float(__float_as_int(np0[p]) ^ sg[p]);
                r0[p] = fmaf(f, coeff, b0[p]);
            }
#pragma unroll
            for (int p = 0; p < 4; ++p) {
                const int x = (acn[p + 4] ^ ap1[p]) + 1;
                const float f = (float)(__clz(x) - 16);
                const float coeff = __int_as_float(__float_as_int(np1[p]) ^ sg[p + 4]);
                r1[p] = fmaf(f, coeff, b1[p]);
            }
            __builtin_nontemporal_store(r0, (float4v*)ob);
            __builtin_nontemporal_store(r1, (float4v*)(ob + 4));
            ob += (size_t)kC * kTP;   // next s row
        }
    }

    // ---- tail: candidate c = 256, lanes 0..7 (p = lane) ----
    if (tid < kTP) {
        const int p  = tid;
        const int cn = cnc[((size_t)t * kC + (kC - 1)) * kTP + p];
        const int a  = abs(cn);
        const unsigned sg = ((unsigned)cn) & 0x80000000u;
        float* ob = out + ((size_t)(t * kS + s0) * kC + (kC - 1)) * kTP + p;
#pragma unroll
        for (int sl = 0; sl < kSB; ++sl) {
            const int x = (a ^ s_apos[sl][p]) + 1;
            const float f = (float)(__clz(x) - 16);
            const float coeff = __int_as_float(__float_as_int(s_np8[sl][p]) ^ sg);
            __builtin_nontemporal_store(fmaf(f, coeff, s_base8[sl][p]),
                                        ob + (size_t)sl * kC * kTP);
        }
    }
}

extern "C" void kernel_launch(void* const* d_in, const int* in_sizes, int n_in,
                              void* d_out, int out_size, void* d_ws, size_t ws_size,
                              hipStream_t stream) {
    const int*   sta = (const int*)d_in[0];
    const int*   pos = (const int*)d_in[1];
    const int*   cnc = (const int*)d_in[2];
    const float* eu  = (const float*)d_in[3];
    float*       out = (float*)d_out;

    const dim3 grid(kT * kTile);   // 2048 blocks: (t, s-tile)
    const dim3 block(256);
    critigraph_kernel<<<grid, block, 0, stream>>>(sta, pos, cnc, eu, out);
}

// Round 7
// 145.724 us; speedup vs baseline: 1.3431x; 1.3431x over previous
//
#include <hip/hip_runtime.h>

// Reference: H=16, TP=8, C=257, T=S=128.  Output float32 (T,S,C,TP).
// ct_val[t,s,c,p] = (sum_p' d(sta[t,p'],pos[t,s,p']) - d(sta[t,p],pos[t,s,p])
//                    + d(cnc[t,c,p],pos[t,s,p])) / 8
// d(c1,c2,norm) = sign(c1>=0)*sign(c2>=0) * (1 - e/16) * norm
//   with e = frexp-exp(float(abs(c1)^abs(c2)+1)) = 32 - clz(xor+1)
//   => d = sign * norm * (clz(xor+1) - 16) / 16    (exact; verified r1==r2)
//
// Round 7: chunk remap for fully-dense stores. r6 showed nt stores regress
// hard (half-covered lines -> partial HBM writes); r5 measured ~5.0 TB/s
// marginal write BW with the 16B-at-32B-stride pattern. Here each lane owns a
// 16B chunk of the flat (C*TP) row: candidate = k>>1, p-half = (k&1)*4. Both
// the cnc load and the out store are contiguous 1KB per wave per instruction
// (the harness fill pattern, which sustains 6.6 TB/s). No nt.

namespace {
constexpr int kTP   = 8;
constexpr int kC    = 257;
constexpr int kT    = 128;
constexpr int kS    = 128;
constexpr int kSB   = 8;              // s per block
constexpr int kTile = kS / kSB;       // 16 s-tiles per t
constexpr int kRow  = kC * kTP;       // 2056 elements per flat row
constexpr int kChunks = kRow / 4;     // 514 16B chunks per row

typedef __attribute__((ext_vector_type(4))) int   int4v;
typedef __attribute__((ext_vector_type(4))) float float4v;
} // namespace

__global__ __launch_bounds__(256) void critigraph_kernel(
    const int*   __restrict__ sta,   // (T,TP)
    const int*   __restrict__ pos,   // (T,S,TP)
    const int*   __restrict__ cnc,   // (T,C,TP)
    const float* __restrict__ eu,    // (T,S)
    float*       __restrict__ out)   // (T,S,C,TP) f32
{
    __shared__ int   s_apos[kSB][kTP];   // |pos|
    __shared__ float s_np8[kSB][kTP];    // sign(pos)*norm/128
    __shared__ float s_csp[kSB][kTP];    // d(sta,pos)
    __shared__ float s_base8[kSB][kTP];  // (sum - csp[p]) / 8

    const int t   = blockIdx.x >> 4;
    const int s0  = (blockIdx.x & (kTile - 1)) * kSB;
    const int tid = threadIdx.x;

    if (tid < kSB * kTP) {
        const int sl = tid >> 3;
        const int p  = tid & 7;
        const int s  = s0 + sl;
        const int st = sta[t * kTP + p];
        const int po = pos[(t * kS + s) * kTP + p];
        const float norm = eu[t * kS + s];
        const int x = (abs(st) ^ abs(po)) + 1;
        const float f = (float)(__clz(x) - 16);
        const float v = f * norm * (1.0f / 16.0f);
        s_csp[sl][p]  = ((st ^ po) < 0) ? -v : v;
        s_apos[sl][p] = abs(po);
        s_np8[sl][p]  = (po >= 0 ? norm : -norm) * (1.0f / 128.0f);
    }
    __syncthreads();
    if (tid < kSB * kTP) {
        const int sl = tid >> 3;
        const int p  = tid & 7;
        float sum = 0.0f;
#pragma unroll
        for (int q = 0; q < kTP; ++q) sum += s_csp[sl][q];
        s_base8[sl][p] = (sum - s_csp[sl][p]) * 0.125f;
    }
    __syncthreads();

    // ---- main: chunks k0 = tid, k1 = tid + 256 (k1 < 512 always) ----
    // chunk k: candidate c = k>>1, p-half ph = (k&1)*4. Flat offsets:
    //   cnc[t] + 4k (ints), out[t,s] + 4k (floats) — identical layouts.
    const int ph = (tid & 1) * 4;           // same parity for k0 and k1
    const int* cb = cnc + (size_t)t * kRow;

    const int4v ca = *(const int4v*)(cb + tid * 4);
    const int4v cc = *(const int4v*)(cb + (tid + 256) * 4);
    int acn0[4], acn1[4];
    unsigned sg0[4], sg1[4];
#pragma unroll
    for (int j = 0; j < 4; ++j) {
        acn0[j] = abs(ca[j]);  sg0[j] = ((unsigned)ca[j]) & 0x80000000u;
        acn1[j] = abs(cc[j]);  sg1[j] = ((unsigned)cc[j]) & 0x80000000u;
    }

    float* orow = out + (size_t)(t * kS + s0) * kRow;
#pragma unroll
    for (int sl = 0; sl < kSB; ++sl) {
        const int4v   ap = *(const int4v*)&s_apos[sl][ph];
        const float4v np = *(const float4v*)&s_np8[sl][ph];
        const float4v b  = *(const float4v*)&s_base8[sl][ph];

        float4v r0, r1;
#pragma unroll
        for (int j = 0; j < 4; ++j) {
            const int x0 = (acn0[j] ^ ap[j]) + 1;
            const float f0 = (float)(__clz(x0) - 16);
            r0[j] = fmaf(f0, __int_as_float(__float_as_int(np[j]) ^ sg0[j]), b[j]);
            const int x1 = (acn1[j] ^ ap[j]) + 1;
            const float f1 = (float)(__clz(x1) - 16);
            r1[j] = fmaf(f1, __int_as_float(__float_as_int(np[j]) ^ sg1[j]), b[j]);
        }
        *(float4v*)(orow + tid * 4)         = r0;   // dense 1KB/wave
        *(float4v*)(orow + (tid + 256) * 4) = r1;   // dense 1KB/wave
        orow += kRow;
    }

    // ---- tail: chunks 512, 513 (candidate 256), lanes 0..1 ----
    if (tid < 2) {
        const int k   = 512 + tid;
        const int php = (k & 1) * 4;
        const int4v ct = *(const int4v*)(cb + k * 4);
        int acn[4]; unsigned sg[4];
#pragma unroll
        for (int j = 0; j < 4; ++j) {
            acn[j] = abs(ct[j]); sg[j] = ((unsigned)ct[j]) & 0x80000000u;
        }
        float* orow2 = out + (size_t)(t * kS + s0) * kRow;
#pragma unroll
        for (int sl = 0; sl < kSB; ++sl) {
            const int4v   ap = *(const int4v*)&s_apos[sl][php];
            const float4v np = *(const float4v*)&s_np8[sl][php];
            const float4v b  = *(const float4v*)&s_base8[sl][php];
            float4v r;
#pragma unroll
            for (int j = 0; j < 4; ++j) {
                const int x = (acn[j] ^ ap[j]) + 1;
                const float f = (float)(__clz(x) - 16);
                r[j] = fmaf(f, __int_as_float(__float_as_int(np[j]) ^ sg[j]), b[j]);
            }
            *(float4v*)(orow2 + k * 4) = r;
            orow2 += kRow;
        }
    }
}

extern "C" void kernel_launch(void* const* d_in, const int* in_sizes, int n_in,
                              void* d_out, int out_size, void* d_ws, size_t ws_size,
                              hipStream_t stream) {
    const int*   sta = (const int*)d_in[0];
    const int*   pos = (const int*)d_in[1];
    const int*   cnc = (const int*)d_in[2];
    const float* eu  = (const float*)d_in[3];
    float*       out = (float*)d_out;

    const dim3 grid(kT * kTile);   // 2048 blocks: (t, s-tile)
    const dim3 block(256);
    critigraph_kernel<<<grid, block, 0, stream>>>(sta, pos, cnc, eu, out);
}